// Round 2
// baseline (701.428 us; speedup 1.0000x reference)
//
#include <hip/hip_runtime.h>
#include <hip/hip_bf16.h>

// GWNN layer: out = (wavelets * filt[None,:]) @ (wavelets_inv @ (features @ W))
// ALL INPUTS/OUTPUT ARE FP32 in global memory (per reference dtypes).
// Internally bf16 MFMA; tolerance (9.56e-2) covers bf16 rounding (~0.03).
//
// Identity: (Wav * filt_cols) @ S == Wav @ (filt_rows * S) -- scale the small
// [8192,64] spectral matrix, never touch the 256 MB wavelet matrices.
//
// v3: the big GEMMs are pure A-streams (A read once, 256 MB fp32; B = 1 MB
// bf16, L2-resident). LDS staging + barriers serialized the memory pipe
// (v1/v2 both ~150us/gemm, ~20% HBM). Now: NO LDS, NO barriers -- each wave
// loads its MFMA A-fragment directly from global (2x f32x4/lane, converts
// in-register) and its B-fragments from L2 (4x dwordx4/lane), 2-deep named
// register pipeline. Waves free-run; HBM stays saturated by 16 waves/CU with
// ~4KB/wave in flight. Floor ~45us/gemm.

typedef unsigned short u16;
typedef short s16x8 __attribute__((ext_vector_type(8)));
typedef float f32x4 __attribute__((ext_vector_type(4)));

__device__ __forceinline__ u16 f2bf(float f) {
    unsigned u;
    __builtin_memcpy(&u, &f, 4);
    unsigned r = (u + 0x7fffu + ((u >> 16) & 1u)) >> 16;  // round-nearest-even
    return (u16)r;
}
__device__ __forceinline__ unsigned pk2(float a, float b) {
    // two fp32 -> packed bf16x2 (RNE), lowers to v_cvt_pk_bf16_f32 on gfx950
    __hip_bfloat162 h = __float22bfloat162_rn(float2{a, b});
    unsigned u;
    __builtin_memcpy(&u, &h, 4);
    return u;
}
__device__ __forceinline__ s16x8 mk_af(f32x4 x, f32x4 y) {
    union { unsigned u[4]; s16x8 v; } r;
    r.u[0] = pk2(x.x, x.y);
    r.u[1] = pk2(x.z, x.w);
    r.u[2] = pk2(y.x, y.y);
    r.u[3] = pk2(y.z, y.w);
    return r.v;
}

#define NN 8192

// ---------------------------------------------------------------------------
// k12: Tt[64][8192] (bf16) = transpose(features[8192][128] @ W[128][64])
// Fused k1+k2: no Tmp round trip. Block b: rows b*64..b*64+63.
// Thread (c = tid&63, w = tid>>6): col c, rows w, w+4, ..., w+60.
__global__ __launch_bounds__(256) void k12_feat_t(const float* __restrict__ F,
                                                  const float* __restrict__ W,
                                                  u16* __restrict__ Tt) {
    __shared__ u16 s[64][65];
    const int tid = threadIdx.x;
    const int c = tid & 63;
    const int w = tid >> 6;
    const int r0 = blockIdx.x * 64;
    float acc[16];
#pragma unroll
    for (int p = 0; p < 16; ++p) acc[p] = 0.f;
    for (int k = 0; k < 128; k += 4) {
        float wv[4];
#pragma unroll
        for (int kk = 0; kk < 4; ++kk) wv[kk] = W[(k + kk) * 64 + c];
#pragma unroll
        for (int p = 0; p < 16; ++p) {
            // wave-uniform address -> broadcast load
            f32x4 fv = *(const f32x4*)(F + (size_t)(r0 + w + 4 * p) * 128 + k);
#pragma unroll
            for (int kk = 0; kk < 4; ++kk) acc[p] += fv[kk] * wv[kk];
        }
    }
#pragma unroll
    for (int p = 0; p < 16; ++p) s[w + 4 * p][c] = f2bf(acc[p]);
    __syncthreads();
    const int j = tid & 63, nq = tid >> 6;
#pragma unroll
    for (int p = 0; p < 16; ++p) {
        int n = nq + p * 4;
        Tt[(size_t)n * NN + r0 + j] = s[j][n];
    }
}

// ---------------------------------------------------------------------------
// gemm v3: P[s][8192][64] fp32 partials = A(fp32, row-major) @ Bt(bf16 [64][NN])^T
// 256 thr = 4 waves, NO LDS, NO barriers. Wave w: output rows m0+w*16..+15,
// all 64 cols. Per K=32 step per lane: A 2x f32x4 (row = l&15 of the wave's
// 16, k-chunk (l>>4)*8), B 4x s16x8 (cols ng*16+(l&15)). 2-deep named-set
// register pipeline hides HBM latency without any barrier drain.
__global__ __launch_bounds__(256) void gemm_direct(const float* __restrict__ A,
                                                   const u16* __restrict__ Bt,
                                                   float* __restrict__ P,
                                                   int kslice) {
    const int tid = threadIdx.x;
    const int w = tid >> 6;
    const int l = tid & 63;
    const int m0 = blockIdx.x * 64;
    const int s = blockIdx.y;
    const int k0 = s * kslice;

    const int row = m0 + w * 16 + (l & 15);
    const int kq = (l >> 4) * 8;

    const float* Ap = A + (size_t)row * NN + k0 + kq;
    const u16* B0 = Bt + (size_t)(l & 15) * NN + k0 + kq;
    const u16* B1 = B0 + (size_t)16 * NN;
    const u16* B2 = B0 + (size_t)32 * NN;
    const u16* B3 = B0 + (size_t)48 * NN;

    f32x4 acc0{0, 0, 0, 0}, acc1{0, 0, 0, 0}, acc2{0, 0, 0, 0}, acc3{0, 0, 0, 0};

    const int nt = kslice / 32;  // even for all split in {1,2,4,8}

    // pipeline register sets (named, compile-time indexed -- rule #20)
    f32x4 aA0, aA1, aB0, aB1;
    s16x8 bA0, bA1, bA2, bA3, bB0, bB1, bB2, bB3;

    // prologue: step 0 -> set A
    aA0 = *(const f32x4*)(Ap + 0);
    aA1 = *(const f32x4*)(Ap + 4);
    bA0 = *(const s16x8*)(B0 + 0);
    bA1 = *(const s16x8*)(B1 + 0);
    bA2 = *(const s16x8*)(B2 + 0);
    bA3 = *(const s16x8*)(B3 + 0);

    for (int t = 0; t < nt; t += 2) {
        // issue loads for step t+1 (set B) -- t+1 <= nt-1 always (nt even)
        {
            const int o = (t + 1) * 32;
            aB0 = *(const f32x4*)(Ap + o);
            aB1 = *(const f32x4*)(Ap + o + 4);
            bB0 = *(const s16x8*)(B0 + o);
            bB1 = *(const s16x8*)(B1 + o);
            bB2 = *(const s16x8*)(B2 + o);
            bB3 = *(const s16x8*)(B3 + o);
        }
        // compute step t from set A
        {
            s16x8 af = mk_af(aA0, aA1);
            acc0 = __builtin_amdgcn_mfma_f32_16x16x32_bf16(af, bA0, acc0, 0, 0, 0);
            acc1 = __builtin_amdgcn_mfma_f32_16x16x32_bf16(af, bA1, acc1, 0, 0, 0);
            acc2 = __builtin_amdgcn_mfma_f32_16x16x32_bf16(af, bA2, acc2, 0, 0, 0);
            acc3 = __builtin_amdgcn_mfma_f32_16x16x32_bf16(af, bA3, acc3, 0, 0, 0);
        }
        // issue loads for step t+2 (set A) -- uniform branch
        if (t + 2 < nt) {
            const int o = (t + 2) * 32;
            aA0 = *(const f32x4*)(Ap + o);
            aA1 = *(const f32x4*)(Ap + o + 4);
            bA0 = *(const s16x8*)(B0 + o);
            bA1 = *(const s16x8*)(B1 + o);
            bA2 = *(const s16x8*)(B2 + o);
            bA3 = *(const s16x8*)(B3 + o);
        }
        // compute step t+1 from set B
        {
            s16x8 af = mk_af(aB0, aB1);
            acc0 = __builtin_amdgcn_mfma_f32_16x16x32_bf16(af, bB0, acc0, 0, 0, 0);
            acc1 = __builtin_amdgcn_mfma_f32_16x16x32_bf16(af, bB1, acc1, 0, 0, 0);
            acc2 = __builtin_amdgcn_mfma_f32_16x16x32_bf16(af, bB2, acc2, 0, 0, 0);
            acc3 = __builtin_amdgcn_mfma_f32_16x16x32_bf16(af, bB3, acc3, 0, 0, 0);
        }
    }

    // epilogue: C/D map col=lane&15, row=(lane>>4)*4+reg  (m89-verified)
    f32x4 accs[4] = {acc0, acc1, acc2, acc3};
    float* Pp = P + (size_t)s * NN * 64;
    const int orow = m0 + w * 16 + (l >> 4) * 4;
    const int ocol = l & 15;
#pragma unroll
    for (int ng = 0; ng < 4; ++ng)
#pragma unroll
        for (int r = 0; r < 4; ++r)
            Pp[(size_t)(orow + r) * 64 + ng * 16 + ocol] = accs[ng][r];
}

// ---------------------------------------------------------------------------
// k4: St[n][j] = bf16( filt[j] * sum_s P[s][j][n] )   (reduce+scale+transpose)
__global__ __launch_bounds__(256) void k4_reduce_scale_t(const float* __restrict__ P,
                                                         const float* __restrict__ filt,
                                                         u16* __restrict__ St,
                                                         int split) {
    __shared__ u16 s[64][65];
    const int tid = threadIdx.x;
    const int j0 = blockIdx.x * 64;
    const int n = tid & 63, jq = tid >> 6;
#pragma unroll 4
    for (int p = 0; p < 16; ++p) {
        int j = jq + p * 4;
        float acc = 0.f;
        for (int t = 0; t < split; ++t)
            acc += P[((size_t)t * NN + j0 + j) * 64 + n];
        acc *= filt[j0 + j];
        s[j][n] = f2bf(acc);
    }
    __syncthreads();
    const int jj = tid & 63, nq = tid >> 6;
#pragma unroll
    for (int p = 0; p < 16; ++p) {
        int nn = nq + p * 4;
        St[(size_t)nn * NN + j0 + jj] = s[jj][nn];
    }
}

// ---------------------------------------------------------------------------
// k6: out[idx] = fp32( sum_s P[s][idx] )
__global__ __launch_bounds__(256) void k6_reduce_out(const float* __restrict__ P,
                                                     float* __restrict__ out,
                                                     int split) {
    const int idx = blockIdx.x * 256 + threadIdx.x;
    float acc = 0.f;
    for (int t = 0; t < split; ++t)
        acc += P[(size_t)t * NN * 64 + idx];
    out[idx] = acc;
}

// ---------------------------------------------------------------------------
extern "C" void kernel_launch(void* const* d_in, const int* in_sizes, int n_in,
                              void* d_out, int out_size, void* d_ws, size_t ws_size,
                              hipStream_t stream) {
    const float* F    = (const float*)d_in[0];  // features   [8192][128]
    const float* W    = (const float*)d_in[1];  // weight     [128][64]
    const float* filt = (const float*)d_in[2];  // filt       [8192]
    const float* Wav  = (const float*)d_in[3];  // wavelets   [8192][8192]
    const float* Winv = (const float*)d_in[4];  // wavelets_inv
    float* out = (float*)d_out;

    char* ws = (char*)d_ws;
    u16* Tt = (u16*)ws;                      // [64][8192] bf16, 1 MB
    u16* St = (u16*)(ws + (1u << 20));       // [64][8192] bf16, 1 MB
    float* P = (float*)(ws + (2u << 20));    // [split][8192][64] fp32, 2 MB each

    // K-split: as many power-of-two slices as ws allows, max 8 (18 MB total)
    size_t per = (size_t)NN * 64 * 4;
    size_t avail = (ws_size > (2u << 20)) ? ws_size - (2u << 20) : per;
    int maxs = (int)(avail / per);
    if (maxs < 1) maxs = 1;
    int split = 1;
    while (split * 2 <= maxs && split < 8) split *= 2;
    int kslice = NN / split;

    // 1. Tt = bf16(features @ W)^T   (fused, no Tmp)
    k12_feat_t<<<128, 256, 0, stream>>>(F, W, Tt);
    // 2. P = Winv @ Tt^T (fp32 partials over K-slices)
    gemm_direct<<<dim3(128, split), 256, 0, stream>>>(Winv, Tt, P, kslice);
    // 3. St = bf16(filt * reduce(P))^T
    k4_reduce_scale_t<<<128, 256, 0, stream>>>(P, filt, St, split);
    // 4. P = Wav @ St^T
    gemm_direct<<<dim3(128, split), 256, 0, stream>>>(Wav, St, P, kslice);
    // 5. out = reduce(P)  (fp32)
    k6_reduce_out<<<2048, 256, 0, stream>>>(P, out, split);
}